// Round 14
// baseline (188.786 us; speedup 1.0000x reference)
//
#include <hip/hip_runtime.h>

#define CC 100000
#define DD 512
#define NTT 1563  // ceil(100000/64)

#define S_SCALE 30.0f
#define COS_M_C 0.8775825618903728f
#define SIN_M_C 0.479425538604203f
#define THRESH_C (-0.8775825618903728f)
#define MM_C 0.2397127693021015f

typedef __attribute__((ext_vector_type(8))) short short8;
typedef __attribute__((ext_vector_type(4))) float f32x4;

static __device__ __forceinline__ unsigned short f2bf(float x) {
  unsigned int u = __float_as_uint(x);
  unsigned int r = (u + 0x7fffu + ((u >> 16) & 1u)) >> 16;
  return (unsigned short)r;
}

#define FENCE() __builtin_amdgcn_sched_barrier(0)

// ---------------------------------------------------------------------------
// Kernel 1: per embedding row i: normalize, bf16, store to wsA in MFMA
// FRAGMENT order (validated r8-r13):
//   byte addr = (k>>5)*32768 + (i>>6)*4096 + ((i>>4)&3)*1024
//             + (((k>>3)&3)*16 + (i&15))*16
// ---------------------------------------------------------------------------
__global__ __launch_bounds__(64) void k1_prep(
    const float* __restrict__ emb, const float* __restrict__ kern,
    const int* __restrict__ label, unsigned short* __restrict__ wsA,
    float* __restrict__ ws_target, float* __restrict__ ws_ctm,
    float* __restrict__ ws_ft) {
  const int i = blockIdx.x;
  const int l = threadIdx.x;

  const float4* er = reinterpret_cast<const float4*>(emb + (size_t)i * DD + l * 8);
  float4 v0 = er[0], v1 = er[1];
  float e[8] = {v0.x, v0.y, v0.z, v0.w, v1.x, v1.y, v1.z, v1.w};

  float esq = 0.f;
#pragma unroll
  for (int j = 0; j < 8; ++j) esq += e[j] * e[j];
#pragma unroll
  for (int o = 32; o > 0; o >>= 1) esq += __shfl_xor(esq, o);
  const float inv = rsqrtf(esq);

  const int c = label[i];
  float dot = 0.f, wsq = 0.f;
#pragma unroll
  for (int j = 0; j < 8; ++j) {
    float w = kern[(size_t)(l * 8 + j) * CC + c];
    dot += e[j] * w;
    wsq += w * w;
  }
#pragma unroll
  for (int o = 32; o > 0; o >>= 1) {
    dot += __shfl_xor(dot, o);
    wsq += __shfl_xor(wsq, o);
  }

  unsigned int pk[4];
#pragma unroll
  for (int j = 0; j < 4; ++j) {
    unsigned int lo = f2bf(e[2 * j] * inv);
    unsigned int hi = f2bf(e[2 * j + 1] * inv);
    pk[j] = lo | (hi << 16);
  }
  const int off = (l >> 2) * 32768 + (i >> 6) * 4096 + (((i >> 4) & 3)) * 1024 +
                  ((l & 3) * 16 + (i & 15)) * 16;
  uint4 v; v.x = pk[0]; v.y = pk[1]; v.z = pk[2]; v.w = pk[3];
  *reinterpret_cast<uint4*>(reinterpret_cast<char*>(wsA) + off) = v;

  if (l == 0) {
    float t = dot * rsqrtf(fmaxf(esq * wsq, 1e-30f));
    t = fminf(fmaxf(t, -1.f), 1.f);
    float st = sqrtf(fmaxf(0.f, 1.f - t * t));
    float ctm = t * COS_M_C - st * SIN_M_C;
    ws_target[i] = t;
    ws_ctm[i] = ctm;
    ws_ft[i] = (t > THRESH_C) ? ctm : (t - MM_C);
  }
}

// ---------------------------------------------------------------------------
// Kernel 2: deterministic reduction of 512 target logits -> t_new
// ---------------------------------------------------------------------------
__global__ __launch_bounds__(64) void k2_tnew(const float* __restrict__ ws_target,
                                              const float* __restrict__ t_in,
                                              float* __restrict__ ws_tnew) {
  const int l = threadIdx.x;
  float s = 0.f;
#pragma unroll
  for (int j = 0; j < 8; ++j) s += ws_target[l * 8 + j];
#pragma unroll
  for (int o = 32; o > 0; o >>= 1) s += __shfl_xor(s, o);
  if (l == 0) ws_tnew[0] = 0.01f * (s * (1.0f / 512.0f)) + 0.99f * t_in[0];
}

// ---------------------------------------------------------------------------
// Kernel 3: 128x64 tile GEMM + epilogue — OCCUPANCY experiment.
// Wave tile shrunk 64x64 -> 64x32 (acc[4][2] = 32 AGPR) so regs/wave drop
// from ~128 to ~88 -> 5-6 waves/SIMD (20-24 waves/CU) instead of the fixed
// 16 waves/CU every clean round so far has run at.
//  - 4 waves/block (2m x 2n), __launch_bounds__(256,5): 102-reg budget.
//  - A: direct global->VGPR fragment loads from fragment-order wsA.
//  - B: r6-pattern LDS double-buffer 2x4KB (64 cols x 32k), one barrier
//    per iter; wave wv supplies k-rows wv*8..+7 of its column (uint4).
//  - 4 mt-siblings of each nt mapped to the SAME XCD (r13-validated):
//    xcd=b&7, mt=(b>>3)&3, nt=(b>>5)*8+xcd -> kern re-reads hit L2.
// Queue per iter (traced): enter [B(kt+1):8]; issue af:4; vmcnt(4)
// retires B:8; BWRITE8; BLOAD8(kt+2); ds_read bfr:2; vmcnt(8) retires
// af:4 (B(kt+2):8 flies over the barrier); lgkm0; 8 MFMA; barrier.
// Tails: kt=14/15 vmcnt(0).
// ---------------------------------------------------------------------------
__global__ __launch_bounds__(256, 5) void k3_gemm(
    const float* __restrict__ kern, const unsigned short* __restrict__ wsA,
    const int* __restrict__ label, const float* __restrict__ ws_ctm,
    const float* __restrict__ ws_ft, const float* __restrict__ ws_tnew,
    float* __restrict__ out) {
  __shared__ __align__(16) char smem[8192 + 2304];  // B 2x4KB + est 4x576B
  __shared__ float colsq[64];

  const int t = threadIdx.x;
  const int l = t & 63;
  const int wv = t >> 6;       // 0..3
  const int mw = wv >> 1;      // m-wave 0..1
  const int nh = (wv & 1) * 32;  // n-half base
  const int lr = l & 15;
  const int lg = l >> 4;

  const int xcd = blockIdx.x & 7;
  const int g = blockIdx.x >> 3;
  const int mt = g & 3;
  const int nt = (g >> 2) * 8 + xcd;
  if (nt >= NTT) return;
  const int n0 = nt * 64;

  if (t < 64) colsq[t] = 0.f;

  const int bn = l;
  const int gcol = n0 + bn;
  const bool colok = gcol < CC;
  const float* bcol = kern + gcol;

  float sumsq = 0.f;

  f32x4 acc[4][2];
#pragma unroll
  for (int a = 0; a < 4; ++a)
#pragma unroll
    for (int b = 0; b < 2; ++b) acc[a][b] = (f32x4){0.f, 0.f, 0.f, 0.f};

  char* Bb = smem;
  const char* pA =
      reinterpret_cast<const char*>(wsA) + (mt * 2 + mw) * 4096 + l * 16;
  // write: wave wv supplies k-slice wv of its column bn (r6 swizzle)
  const int wb = bn * 64 + (((wv ^ (bn & 3) ^ ((bn >> 2) & 3))) << 4);

#define BLOAD8(KT, r0, r1, r2, r3, r4, r5, r6, r7)                       \
  {                                                                      \
    if (colok) {                                                         \
      const float* q_ = bcol + (size_t)((KT) * 32 + wv * 8) * CC;        \
      r0 = q_[0];              r1 = q_[(size_t)CC];                      \
      r2 = q_[(size_t)2 * CC]; r3 = q_[(size_t)3 * CC];                  \
      r4 = q_[(size_t)4 * CC]; r5 = q_[(size_t)5 * CC];                  \
      r6 = q_[(size_t)6 * CC]; r7 = q_[(size_t)7 * CC];                  \
    } else {                                                             \
      r0 = r1 = r2 = r3 = r4 = r5 = r6 = r7 = 0.f;                       \
    }                                                                    \
  }

#define BWRITE8(KT, r0, r1, r2, r3, r4, r5, r6, r7)                      \
  {                                                                      \
    sumsq += r0 * r0 + r1 * r1 + r2 * r2 + r3 * r3 + r4 * r4 + r5 * r5 + \
             r6 * r6 + r7 * r7;                                          \
    uint4 pk_;                                                           \
    pk_.x = (unsigned int)f2bf(r0) | ((unsigned int)f2bf(r1) << 16);     \
    pk_.y = (unsigned int)f2bf(r2) | ((unsigned int)f2bf(r3) << 16);     \
    pk_.z = (unsigned int)f2bf(r4) | ((unsigned int)f2bf(r5) << 16);     \
    pk_.w = (unsigned int)f2bf(r6) | ((unsigned int)f2bf(r7) << 16);     \
    *reinterpret_cast<uint4*>(Bb + ((KT)&1) * 4096 + wb) = pk_;          \
  }

  // ---- prologue ----
  float q0, q1, q2, q3, q4, q5, q6, q7;  // B(0)
  float p0, p1, p2, p3, p4, p5, p6, p7;  // B(kt+1), loop-carried
  BLOAD8(0, q0, q1, q2, q3, q4, q5, q6, q7);
  FENCE();
  BLOAD8(1, p0, p1, p2, p3, p4, p5, p6, p7);
  FENCE();
  // queue: [B0:8, B1:8]
  asm volatile("s_waitcnt vmcnt(8)" ::: "memory");  // B0 landed
  BWRITE8(0, q0, q1, q2, q3, q4, q5, q6, q7);
  asm volatile("s_waitcnt lgkmcnt(0)" ::: "memory");
  FENCE();
  __builtin_amdgcn_s_barrier();
  FENCE();
  // enter loop: queue = [B1:8]

  for (int kt = 0; kt < 16; ++kt) {
    const int cur = kt & 1;
    // 1. issue A fragment loads (direct from global, L2-hot)
    short8 af[4];
#pragma unroll
    for (int mf = 0; mf < 4; ++mf)
      af[mf] = *reinterpret_cast<const short8*>(pA + kt * 32768 + mf * 1024);
    FENCE();
    // 2-4. retire B(kt+1) regs (iter-old), commit, issue B(kt+2)
    if (kt < 15) {
      asm volatile("s_waitcnt vmcnt(4)" ::: "memory");
      BWRITE8(kt + 1, p0, p1, p2, p3, p4, p5, p6, p7);
    }
    if (kt < 14) {
      BLOAD8(kt + 2, p0, p1, p2, p3, p4, p5, p6, p7);
    }
    FENCE();
    // 5. B fragment ds_reads (wave's 32-col half)
    short8 bfr[2];
#pragma unroll
    for (int nf = 0; nf < 2; ++nf) {
      const int n = nh + nf * 16 + lr;
      bfr[nf] = *reinterpret_cast<const short8*>(
          Bb + cur * 4096 + n * 64 + (((lg ^ (n & 3) ^ ((n >> 2) & 3))) << 4));
    }
    // 6. af landed (B(kt+2) stays in flight across the barrier)
    if (kt < 14) {
      asm volatile("s_waitcnt vmcnt(8)" ::: "memory");
    } else {
      asm volatile("s_waitcnt vmcnt(0)" ::: "memory");
    }
    asm volatile("s_waitcnt lgkmcnt(0)" ::: "memory");
    FENCE();
    // 7. MFMA (8)
    __builtin_amdgcn_s_setprio(1);
#pragma unroll
    for (int mf = 0; mf < 4; ++mf)
#pragma unroll
      for (int nf = 0; nf < 2; ++nf)
        acc[mf][nf] = __builtin_amdgcn_mfma_f32_16x16x32_bf16(
            af[mf], bfr[nf], acc[mf][nf], 0, 0, 0);
    __builtin_amdgcn_s_setprio(0);
    FENCE();
    // 8. single barrier (4 waves)
    __builtin_amdgcn_s_barrier();
    FENCE();
  }

  // ---- column-norm reduce (4 waves, disjoint k-slices) ----
  atomicAdd(&colsq[bn], sumsq);
  asm volatile("s_waitcnt lgkmcnt(0)" ::: "memory");
  FENCE();
  __builtin_amdgcn_s_barrier();
  FENCE();

  const float tnew = ws_tnew[0];
  float invn[2];
#pragma unroll
  for (int nf = 0; nf < 2; ++nf)
    invn[nf] = rsqrtf(fmaxf(colsq[nh + nf * 16 + lr], 1e-30f));

  // ---- epilogue: 4-row phased transpose, float2 stores ----
  float* est = reinterpret_cast<float*>(smem + 8192) + (size_t)wv * 144;  // 4x36
  const int c2 = n0 + nh + lr * 2;
#pragma unroll
  for (int mf = 0; mf < 4; ++mf) {
#pragma unroll
    for (int p = 0; p < 4; ++p) {
      asm volatile("s_waitcnt lgkmcnt(0)" ::: "memory");  // WAR vs prev phase
      FENCE();
      if (lg == p) {
#pragma unroll
        for (int r = 0; r < 4; ++r)
#pragma unroll
          for (int nf = 0; nf < 2; ++nf)
            est[r * 36 + nf * 16 + lr] = acc[mf][nf][r] * invn[nf];
      }
      asm volatile("s_waitcnt lgkmcnt(0)" ::: "memory");  // RAW
      FENCE();
      const int m = mt * 128 + mw * 64 + mf * 16 + p * 4 + lg;
      const float ctm = ws_ctm[m];
      const float ft = ws_ft[m];
      const int lab = label[m];
      float2 vv = *reinterpret_cast<const float2*>(&est[lg * 36 + lr * 2]);
      if (c2 < CC) {  // c2 even -> c2+1 also < CC
        float ov[2] = {vv.x, vv.y};
#pragma unroll
        for (int jj = 0; jj < 2; ++jj) {
          float cosv = fminf(fmaxf(ov[jj], -1.f), 1.f);
          float val = (cosv > ctm) ? cosv * (tnew + cosv) : cosv;
          if (c2 + jj == lab) val = ft;
          ov[jj] = val * S_SCALE;
        }
        float2 st2;
        st2.x = ov[0]; st2.y = ov[1];
        *reinterpret_cast<float2*>(out + (size_t)m * CC + c2) = st2;
      }
    }
  }
#undef BLOAD8
#undef BWRITE8
}

// ---------------------------------------------------------------------------
extern "C" void kernel_launch(void* const* d_in, const int* in_sizes, int n_in,
                              void* d_out, int out_size, void* d_ws,
                              size_t ws_size, hipStream_t stream) {
  (void)in_sizes; (void)n_in; (void)out_size; (void)ws_size;
  const float* emb = (const float*)d_in[0];
  const float* kern = (const float*)d_in[1];
  const int* label = (const int*)d_in[2];
  const float* t_in = (const float*)d_in[3];
  float* out = (float*)d_out;

  char* ws = (char*)d_ws;
  unsigned short* wsA = (unsigned short*)ws;
  float* ws_target = (float*)(ws + 524288);
  float* ws_ctm = (float*)(ws + 526336);
  float* ws_ft = (float*)(ws + 528384);
  float* ws_tnew = (float*)(ws + 530432);

  k1_prep<<<512, 64, 0, stream>>>(emb, kern, label, wsA, ws_target, ws_ctm, ws_ft);
  k2_tnew<<<1, 64, 0, stream>>>(ws_target, t_in, ws_tnew);
  // grid: 196 nt-groups x 4 mt x 8 xcd = 6272 blocks (nt >= 1563 exit early)
  k3_gemm<<<196 * 32, 256, 0, stream>>>(kern, wsA, label, ws_ctm, ws_ft,
                                        ws_tnew, out);
}